// Round 1
// baseline (2996.859 us; speedup 1.0000x reference)
//
#include <hip/hip_runtime.h>
#include <math.h>

#define BATCH 256
#define LEN   10000
#define C0 64
#define P0 624
#define T1 155
#define P1 77

// ws offsets (in floats)
#define OFF_CONST 0
#define OFF_Y0    160
#define OFF_Y1    2560160
#define OFF_X     12783776
#define OFF_H0    15306912
#define OFF_C0    15437984
#define OFF_H1    15503520
#define OFF_C1    15634592
#define OFF_Z0    15700128
#define OFF_Z1    15831200
#define OFF_TMP   15962272
// total 21,041,312 floats = 84.2 MB

// ---------------- host-side savgol constants (pinv via 4x4 normal equations) --------------
static void invert4(const double A[4][4], double inv[4][4]) {
  double M[4][8];
  for (int i = 0; i < 4; ++i)
    for (int j = 0; j < 4; ++j) { M[i][j] = A[i][j]; M[i][j+4] = (i==j) ? 1.0 : 0.0; }
  for (int col = 0; col < 4; ++col) {
    int p = col;
    for (int r = col+1; r < 4; ++r) if (fabs(M[r][col]) > fabs(M[p][col])) p = r;
    if (p != col) for (int j = 0; j < 8; ++j) { double t = M[col][j]; M[col][j] = M[p][j]; M[p][j] = t; }
    double d = M[col][col];
    for (int j = 0; j < 8; ++j) M[col][j] /= d;
    for (int r = 0; r < 4; ++r) if (r != col) {
      double f = M[r][col];
      for (int j = 0; j < 8; ++j) M[r][j] -= f * M[col][j];
    }
  }
  for (int i = 0; i < 4; ++i) for (int j = 0; j < 4; ++j) inv[i][j] = M[i][j+4];
}

static void compute_consts(float* out) {
  { // interior taps: t = -5..5, row 0 of pinv(V)
    double V[11][4], A[4][4], inv[4][4];
    for (int w = 0; w < 11; ++w) { double t = (double)(w-5), pw = 1.0; for (int m = 0; m < 4; ++m) { V[w][m] = pw; pw *= t; } }
    for (int m = 0; m < 4; ++m) for (int n = 0; n < 4; ++n) { double s = 0; for (int w = 0; w < 11; ++w) s += V[w][m]*V[w][n]; A[m][n] = s; }
    invert4(A, inv);
    for (int w = 0; w < 11; ++w) { double s = 0; for (int m = 0; m < 4; ++m) s += inv[0][m]*V[w][m]; out[w] = (float)s; }
  }
  { // edge windows: nodes 0..10, pe = pinv(Ve); eval at 0..4 and 6..10
    double V[11][4], A[4][4], inv[4][4], pe[4][11];
    for (int w = 0; w < 11; ++w) { double t = (double)w, pw = 1.0; for (int m = 0; m < 4; ++m) { V[w][m] = pw; pw *= t; } }
    for (int m = 0; m < 4; ++m) for (int n = 0; n < 4; ++n) { double s = 0; for (int w = 0; w < 11; ++w) s += V[w][m]*V[w][n]; A[m][n] = s; }
    invert4(A, inv);
    for (int m = 0; m < 4; ++m) for (int w = 0; w < 11; ++w) { double s = 0; for (int n = 0; n < 4; ++n) s += inv[m][n]*V[w][n]; pe[m][w] = s; }
    for (int w = 0; w < 11; ++w) for (int k = 0; k < 5; ++k) {
      double s = 0, pk = 1.0;
      for (int m = 0; m < 4; ++m) { s += pe[m][w]*pk; pk *= (double)k; }
      out[16 + w*5 + k] = (float)s;
    }
    for (int w = 0; w < 11; ++w) for (int k = 0; k < 5; ++k) {
      double tv = (double)(6+k), s = 0, pk = 1.0;
      for (int m = 0; m < 4; ++m) { s += pe[m][w]*pk; pk *= tv; }
      out[80 + w*5 + k] = (float)s;
    }
  }
}

// ---------------- savgol: (256,10000) -> y0 ----------------
__global__ __launch_bounds__(256) void k_savgol(const float* __restrict__ x,
                                                const float* __restrict__ C,
                                                float* __restrict__ y0) {
  int i = blockIdx.x * 256 + threadIdx.x;
  int b = blockIdx.y;
  if (i >= LEN) return;
  const float* xb = x + b * LEN;
  float r = 0.f;
  if (i < 5) {
#pragma unroll
    for (int w = 0; w < 11; ++w) r += xb[w] * C[16 + w*5 + i];
  } else if (i >= LEN-5) {
    int k = i - (LEN-5);
#pragma unroll
    for (int w = 0; w < 11; ++w) r += xb[LEN-11 + w] * C[80 + w*5 + k];
  } else {
#pragma unroll
    for (int w = 0; w < 11; ++w) r += xb[i-5+w] * C[w];
  }
  y0[b*LEN + i] = r;
}

// ---------------- conv0 + relu + pool2 + bn: y0 -> y1 (256,64,624) ----------------
// thread = one pooled position uu; loops 64 oc with wave-uniform (scalar) weight loads
__global__ __launch_bounds__(256) void k_conv0(const float* __restrict__ y0,
    const float* __restrict__ w0, const float* __restrict__ cb0,
    const float* __restrict__ bg0, const float* __restrict__ bb0,
    const float* __restrict__ bm0, const float* __restrict__ bv0,
    float* __restrict__ y1) {
  int b = blockIdx.y;
  int uu = blockIdx.x * 256 + threadIdx.x;
  if (uu >= P0) return;
  const float4* p = reinterpret_cast<const float4*>(y0 + b*LEN + 16*uu);
  float iv[24];
#pragma unroll
  for (int j = 0; j < 6; ++j) {
    float4 q = p[j];
    iv[4*j] = q.x; iv[4*j+1] = q.y; iv[4*j+2] = q.z; iv[4*j+3] = q.w;
  }
  for (int oc = 0; oc < C0; ++oc) {
    float bias = cb0[oc];
    float s0 = bias, s1 = bias;
#pragma unroll
    for (int k = 0; k < 16; ++k) {
      float wk = w0[oc*16 + k];
      s0 += iv[k]   * wk;
      s1 += iv[k+8] * wk;
    }
    s0 = fmaxf(s0, 0.f); s1 = fmaxf(s1, 0.f);
    float pm = fmaxf(s0, s1);
    float sc = bg0[oc] * rsqrtf(bv0[oc] + 1e-5f);
    y1[b*(C0*P0) + oc*P0 + uu] = pm*sc + (bb0[oc] - bm0[oc]*sc);
  }
}

// ---------------- conv1 as im2col GEMM: (39680 x 128, K=512) -> tmp (b,t,oc) ----------------
__global__ __launch_bounds__(256) void k_conv1_gemm(const float* __restrict__ y1,
    const float* __restrict__ w1, const float* __restrict__ cb1,
    float* __restrict__ tmp) {
  __shared__ __align__(16) float sa[128*33];
  __shared__ __align__(16) float sw[128*33];
  int m0 = blockIdx.x * 128;
  int tid = threadIdx.x;
  int c  = tid & 31;    // k-local column (fixed per thread)
  int r0 = tid >> 5;    // row base for loads
  int ybase[16];
#pragma unroll
  for (int it = 0; it < 16; ++it) {
    int m = m0 + r0 + 8*it;
    int bb = m / 155;
    int t  = m - bb*155;
    ybase[it] = bb*(C0*P0) + 4*t;
  }
  int cciq = c >> 3, ck = c & 7;
  float acc[8][8] = {{0.f}};
  int mg = tid >> 4;   // 0..15
  int ng = tid & 15;   // 0..15
  for (int kc = 0; kc < 512; kc += 32) {
    int ci0 = kc >> 3;
    int aoff = (ci0 + cciq)*P0 + ck;
#pragma unroll
    for (int it = 0; it < 16; ++it) {
      int rl = r0 + 8*it;
      sa[rl*33 + c] = y1[ybase[it] + aoff];
      sw[rl*33 + c] = w1[rl*512 + kc + c];
    }
    __syncthreads();
#pragma unroll
    for (int k = 0; k < 32; ++k) {
      float av[8], wv[8];
#pragma unroll
      for (int i = 0; i < 8; ++i) av[i] = sa[(mg*8+i)*33 + k];
#pragma unroll
      for (int j = 0; j < 8; ++j) wv[j] = sw[(16*j+ng)*33 + k];
#pragma unroll
      for (int i = 0; i < 8; ++i)
#pragma unroll
        for (int j = 0; j < 8; ++j) acc[i][j] += av[i]*wv[j];
    }
    __syncthreads();
  }
#pragma unroll
  for (int j = 0; j < 8; ++j) {
    int n = 16*j + ng;
    float bias = cb1[n];
#pragma unroll
    for (int i = 0; i < 8; ++i) {
      int m = m0 + mg*8 + i;
      tmp[m*128 + n] = acc[i][j] + bias;
    }
  }
}

// ---------------- relu + pool2 + bn: tmp -> X (77,256,128) t-major ----------------
__global__ __launch_bounds__(256) void k_pool1(const float* __restrict__ tmp,
    const float* __restrict__ bg1, const float* __restrict__ bb1,
    const float* __restrict__ bm1, const float* __restrict__ bv1,
    float* __restrict__ X) {
  int idx = blockIdx.x*256 + threadIdx.x;   // < 77*256*128
  int u  = idx >> 15;
  int rr = idx & 32767;
  int bb = rr >> 7;
  int oc = rr & 127;
  int base = (bb*155 + 2*u)*128 + oc;
  float t0 = tmp[base], t1 = tmp[base + 128];
  float pm = fmaxf(0.f, fmaxf(t0, t1));
  float sc = bg1[oc] * rsqrtf(bv1[oc] + 1e-5f);
  X[idx] = pm*sc + (bb1[oc] - bm1[oc]*sc);
}

// ---------------- pipelined LSTM step: launch s runs layer0 step s and layer1 step s-1 ----------------
// 512 blocks x 64 threads. Per layer: 256 blocks = 8 b-tiles(32) x 32 u-tiles(8).
// Thread computes 4b x 4gates via outer product from k-major LDS tiles (float4 fragment reads).
__global__ __launch_bounds__(64) void k_lstm_step(const float* __restrict__ X,
    const float* __restrict__ Wih0, const float* __restrict__ Whh0,
    const float* __restrict__ bih0, const float* __restrict__ bhh0,
    const float* __restrict__ Wih1, const float* __restrict__ Whh1,
    const float* __restrict__ bih1, const float* __restrict__ bhh1,
    float* __restrict__ h0buf, float* __restrict__ c0,
    float* __restrict__ h1buf, float* __restrict__ c1,
    int s) {
  int blk = blockIdx.x;
  int layer = blk >> 8;
  if (layer == 0) { if (s >= 77) return; } else { if (s < 1) return; }
  int lb = blk & 255;
  int b0 = (lb >> 5) * 32;
  int u0 = (lb & 31) * 8;
  int tid = threadIdx.x;
  int u_l = tid & 7, bg = tid >> 3;
  const float* h0r = h0buf + (s & 1) * 65536;
  float*       h0w = h0buf + ((s + 1) & 1) * 65536;
  const float* h1r = h1buf + (s & 1) * 65536;
  float*       h1w = h1buf + ((s + 1) & 1) * 65536;
  int t = layer ? (s - 1) : s;

  __shared__ __align__(16) float a_t[32*36];  // [k][b_local]
  __shared__ __align__(16) float w_t[32*36];  // [k][u_l*4+g]
  float acc[4][4] = {{0.f}};
  int K = layer ? 512 : 384;
  for (int kc = 0; kc < K; kc += 32) {
    const float* aptr; int astr, aoff;
    const float* wptr; int wstr, woff;
    if (layer == 0) {
      if (kc < 128) { aptr = X + t*32768; astr = 128; aoff = kc;     wptr = Wih0; wstr = 128; woff = kc; }
      else          { aptr = h0r;         astr = 256; aoff = kc-128; wptr = Whh0; wstr = 256; woff = kc-128; }
    } else {
      if (kc < 256) { aptr = h0r;         astr = 256; aoff = kc;     wptr = Wih1; wstr = 256; woff = kc; }
      else          { aptr = h1r;         astr = 256; aoff = kc-256; wptr = Whh1; wstr = 256; woff = kc-256; }
    }
#pragma unroll
    for (int it = 0; it < 16; ++it) {
      int i = tid + 64*it;
      int row = i >> 5, col = i & 31;
      a_t[col*36 + row] = aptr[(b0+row)*astr + aoff + col];
      int g = row >> 3, ul = row & 7;
      int jj = g*256 + u0 + ul;
      w_t[col*36 + ul*4 + g] = wptr[jj*wstr + woff + col];
    }
    __syncthreads();
#pragma unroll
    for (int k = 0; k < 32; ++k) {
      float4 av4 = *reinterpret_cast<const float4*>(&a_t[k*36 + bg*4]);
      float4 wv4 = *reinterpret_cast<const float4*>(&w_t[k*36 + u_l*4]);
      float av[4] = {av4.x, av4.y, av4.z, av4.w};
      float wv[4] = {wv4.x, wv4.y, wv4.z, wv4.w};
#pragma unroll
      for (int i = 0; i < 4; ++i)
#pragma unroll
        for (int g = 0; g < 4; ++g) acc[i][g] += av[i]*wv[g];
    }
    __syncthreads();
  }
  int uu = u0 + u_l;
  const float* bi = layer ? bih1 : bih0;
  const float* bh = layer ? bhh1 : bhh0;
  float bsum[4];
#pragma unroll
  for (int g = 0; g < 4; ++g) bsum[g] = bi[g*256 + uu] + bh[g*256 + uu];
  float* cc = layer ? c1 : c0;
  float* hw = layer ? h1w : h0w;
#pragma unroll
  for (int i = 0; i < 4; ++i) {
    int bb = b0 + bg*4 + i;
    float gi = acc[i][0] + bsum[0];
    float gf = acc[i][1] + bsum[1];
    float gg = acc[i][2] + bsum[2];
    float go = acc[i][3] + bsum[3];
    float si = 1.f/(1.f + expf(-gi));
    float sf = 1.f/(1.f + expf(-gf));
    float so = 1.f/(1.f + expf(-go));
    float tg = tanhf(gg);
    float cn = sf*cc[bb*256 + uu] + si*tg;
    cc[bb*256 + uu] = cn;
    hw[bb*256 + uu] = so * tanhf(cn);
  }
}

// ---------------- FC: C = act(A @ W^T + b), M=256 ----------------
__global__ __launch_bounds__(256) void k_fc(const float* __restrict__ A,
    const float* __restrict__ W, const float* __restrict__ bias,
    float* __restrict__ Cout, int N, int K, int kshift, int dorelu) {
  __shared__ __align__(16) float sa[16*516];
  int m0 = blockIdx.y * 16;
  int n = blockIdx.x * 16 + (threadIdx.x & 15);
  int m = threadIdx.x >> 4;
  int stride = K + 4;
  for (int i = threadIdx.x; i < 16*K; i += 256) {
    int mm = i >> kshift;
    int kk = i - (mm << kshift);
    sa[mm*stride + kk] = A[(m0+mm)*K + kk];
  }
  __syncthreads();
  const float4* wr = reinterpret_cast<const float4*>(W + n*K);
  const float4* ar = reinterpret_cast<const float4*>(sa + m*stride);
  float acc = 0.f;
  int kq4 = K >> 2;
  for (int kq = 0; kq < kq4; ++kq) {
    float4 wv = wr[kq], av = ar[kq];
    acc += av.x*wv.x + av.y*wv.y + av.z*wv.z + av.w*wv.w;
  }
  acc += bias[n];
  if (dorelu) acc = fmaxf(acc, 0.f);
  Cout[(m0+m)*N + n] = acc;
}

extern "C" void kernel_launch(void* const* d_in, const int* in_sizes, int n_in,
                              void* d_out, int out_size, void* d_ws, size_t ws_size,
                              hipStream_t stream) {
  const float* x       = (const float*)d_in[0];
  const float* conv_w0 = (const float*)d_in[1];
  const float* conv_b0 = (const float*)d_in[2];
  const float* bn_g0   = (const float*)d_in[3];
  const float* bn_b0   = (const float*)d_in[4];
  const float* bn_m0   = (const float*)d_in[5];
  const float* bn_v0   = (const float*)d_in[6];
  const float* conv_w1 = (const float*)d_in[7];
  const float* conv_b1 = (const float*)d_in[8];
  const float* bn_g1   = (const float*)d_in[9];
  const float* bn_b1   = (const float*)d_in[10];
  const float* bn_m1   = (const float*)d_in[11];
  const float* bn_v1   = (const float*)d_in[12];
  const float* Wih0    = (const float*)d_in[13];
  const float* Whh0    = (const float*)d_in[14];
  const float* bih0    = (const float*)d_in[15];
  const float* bhh0    = (const float*)d_in[16];
  const float* Wih1    = (const float*)d_in[17];
  const float* Whh1    = (const float*)d_in[18];
  const float* bih1    = (const float*)d_in[19];
  const float* bhh1    = (const float*)d_in[20];
  const float* fc0_w   = (const float*)d_in[21];
  const float* fc0_b   = (const float*)d_in[22];
  const float* fc1_w   = (const float*)d_in[23];
  const float* fc1_b   = (const float*)d_in[24];
  const float* out_w   = (const float*)d_in[25];
  const float* out_b   = (const float*)d_in[26];
  float* ws = (float*)d_ws;
  float* out = (float*)d_out;

  static float h_consts[160];
  compute_consts(h_consts);
  hipMemcpyAsync(ws + OFF_CONST, h_consts, 160*sizeof(float), hipMemcpyHostToDevice, stream);
  // zero LSTM states (h0 ping-pong, c0, h1 ping-pong, c1) — contiguous
  hipMemsetAsync(ws + OFF_H0, 0, 393216*sizeof(float), stream);

  k_savgol<<<dim3(40, BATCH), 256, 0, stream>>>(x, ws + OFF_CONST, ws + OFF_Y0);
  k_conv0<<<dim3(3, BATCH), 256, 0, stream>>>(ws + OFF_Y0, conv_w0, conv_b0,
                                              bn_g0, bn_b0, bn_m0, bn_v0, ws + OFF_Y1);
  k_conv1_gemm<<<310, 256, 0, stream>>>(ws + OFF_Y1, conv_w1, conv_b1, ws + OFF_TMP);
  k_pool1<<<9856, 256, 0, stream>>>(ws + OFF_TMP, bn_g1, bn_b1, bn_m1, bn_v1, ws + OFF_X);
  for (int s = 0; s <= 77; ++s) {
    k_lstm_step<<<512, 64, 0, stream>>>(ws + OFF_X, Wih0, Whh0, bih0, bhh0,
                                        Wih1, Whh1, bih1, bhh1,
                                        ws + OFF_H0, ws + OFF_C0, ws + OFF_H1, ws + OFF_C1, s);
  }
  // final h1 lands in h1buf parity 0 (written at s=77 into buf[(77+1)&1]=0)
  k_fc<<<dim3(32, 16), 256, 0, stream>>>(ws + OFF_H1, fc0_w, fc0_b, ws + OFF_Z0, 512, 256, 8, 1);
  k_fc<<<dim3(32, 16), 256, 0, stream>>>(ws + OFF_Z0, fc1_w, fc1_b, ws + OFF_Z1, 512, 512, 9, 1);
  k_fc<<<dim3(16, 16), 256, 0, stream>>>(ws + OFF_Z1, out_w, out_b, out, 256, 512, 9, 0);
}

// Round 2
// 1796.839 us; speedup vs baseline: 1.6679x; 1.6679x over previous
//
#include <hip/hip_runtime.h>
#include <math.h>

#define BATCH 256
#define LEN   10000
#define C0 64
#define P0 624
#define T1 155
#define P1 77

// ws offsets (in floats)
#define OFF_CONST 0
#define OFF_Y0    160
#define OFF_Y1    2560160
#define OFF_X     12783776
#define OFF_H0    15306912
#define OFF_C0    15437984
#define OFF_H1    15503520
#define OFF_C1    15634592
#define OFF_Z0    15700128
#define OFF_Z1    15831200
#define OFF_TMP   15962272

// ---------------- host-side savgol constants ----------------
static void invert4(const double A[4][4], double inv[4][4]) {
  double M[4][8];
  for (int i = 0; i < 4; ++i)
    for (int j = 0; j < 4; ++j) { M[i][j] = A[i][j]; M[i][j+4] = (i==j) ? 1.0 : 0.0; }
  for (int col = 0; col < 4; ++col) {
    int p = col;
    for (int r = col+1; r < 4; ++r) if (fabs(M[r][col]) > fabs(M[p][col])) p = r;
    if (p != col) for (int j = 0; j < 8; ++j) { double t = M[col][j]; M[col][j] = M[p][j]; M[p][j] = t; }
    double d = M[col][col];
    for (int j = 0; j < 8; ++j) M[col][j] /= d;
    for (int r = 0; r < 4; ++r) if (r != col) {
      double f = M[r][col];
      for (int j = 0; j < 8; ++j) M[r][j] -= f * M[col][j];
    }
  }
  for (int i = 0; i < 4; ++i) for (int j = 0; j < 4; ++j) inv[i][j] = M[i][j+4];
}

static void compute_consts(float* out) {
  {
    double V[11][4], A[4][4], inv[4][4];
    for (int w = 0; w < 11; ++w) { double t = (double)(w-5), pw = 1.0; for (int m = 0; m < 4; ++m) { V[w][m] = pw; pw *= t; } }
    for (int m = 0; m < 4; ++m) for (int n = 0; n < 4; ++n) { double s = 0; for (int w = 0; w < 11; ++w) s += V[w][m]*V[w][n]; A[m][n] = s; }
    invert4(A, inv);
    for (int w = 0; w < 11; ++w) { double s = 0; for (int m = 0; m < 4; ++m) s += inv[0][m]*V[w][m]; out[w] = (float)s; }
  }
  {
    double V[11][4], A[4][4], inv[4][4], pe[4][11];
    for (int w = 0; w < 11; ++w) { double t = (double)w, pw = 1.0; for (int m = 0; m < 4; ++m) { V[w][m] = pw; pw *= t; } }
    for (int m = 0; m < 4; ++m) for (int n = 0; n < 4; ++n) { double s = 0; for (int w = 0; w < 11; ++w) s += V[w][m]*V[w][n]; A[m][n] = s; }
    invert4(A, inv);
    for (int m = 0; m < 4; ++m) for (int w = 0; w < 11; ++w) { double s = 0; for (int n = 0; n < 4; ++n) s += inv[m][n]*V[w][n]; pe[m][w] = s; }
    for (int w = 0; w < 11; ++w) for (int k = 0; k < 5; ++k) {
      double s = 0, pk = 1.0;
      for (int m = 0; m < 4; ++m) { s += pe[m][w]*pk; pk *= (double)k; }
      out[16 + w*5 + k] = (float)s;
    }
    for (int w = 0; w < 11; ++w) for (int k = 0; k < 5; ++k) {
      double tv = (double)(6+k), s = 0, pk = 1.0;
      for (int m = 0; m < 4; ++m) { s += pe[m][w]*pk; pk *= tv; }
      out[80 + w*5 + k] = (float)s;
    }
  }
}

// ---------------- fused savgol + conv0 + relu + pool2 + bn: x -> y1 (256,64,624) ----------------
// Right-edge savgol outputs (pos >= 9995) are never consumed by conv0 (max input pos 9991),
// so only uu==0 needs the left-edge polynomial path.
__global__ __launch_bounds__(256) void k_sgconv0(const float* __restrict__ x,
    const float* __restrict__ Cc,
    const float* __restrict__ w0, const float* __restrict__ cb0,
    const float* __restrict__ bg0, const float* __restrict__ bb0,
    const float* __restrict__ bm0, const float* __restrict__ bv0,
    float* __restrict__ y1) {
  __shared__ float sw[1024];
  __shared__ float s_sc[64], s_off[64], s_cb[64];
  int tid = threadIdx.x;
  for (int i = tid; i < 1024; i += 256) sw[i] = w0[i];
  if (tid < 64) {
    float sc = bg0[tid] * rsqrtf(bv0[tid] + 1e-5f);
    s_sc[tid] = sc;
    s_off[tid] = bb0[tid] - bm0[tid]*sc;
    s_cb[tid] = cb0[tid];
  }
  __syncthreads();
  int b = blockIdx.y;
  int uu = blockIdx.x*256 + tid;
  if (uu >= P0) return;
  const float* xb = x + b*LEN;
  float hC[11];
#pragma unroll
  for (int w = 0; w < 11; ++w) hC[w] = Cc[w];
  float iv[24];
  if (uu == 0) {
    float xx[32];
    const float4* p = reinterpret_cast<const float4*>(xb);
#pragma unroll
    for (int j = 0; j < 8; ++j) { float4 v = p[j]; xx[4*j]=v.x; xx[4*j+1]=v.y; xx[4*j+2]=v.z; xx[4*j+3]=v.w; }
#pragma unroll
    for (int j = 0; j < 24; ++j) {
      float s = 0.f;
      if (j < 5) {
        for (int w = 0; w < 11; ++w) s += xx[w] * Cc[16 + w*5 + j];
      } else {
        for (int w = 0; w < 11; ++w) s += xx[j-5+w] * hC[w];
      }
      iv[j] = s;
    }
  } else {
    float xx[40];
    const float4* p = reinterpret_cast<const float4*>(xb + 16*uu - 8);
#pragma unroll
    for (int j = 0; j < 10; ++j) { float4 v = p[j]; xx[4*j]=v.x; xx[4*j+1]=v.y; xx[4*j+2]=v.z; xx[4*j+3]=v.w; }
#pragma unroll
    for (int j = 0; j < 24; ++j) {
      float s = 0.f;
#pragma unroll
      for (int w = 0; w < 11; ++w) s += xx[j+3+w] * hC[w];
      iv[j] = s;
    }
  }
  int obase = b*(C0*P0) + uu;
  for (int oc = 0; oc < 64; ++oc) {
    float bias = s_cb[oc];
    float s0 = bias, s1 = bias;
#pragma unroll
    for (int k = 0; k < 16; ++k) {
      float wk = sw[oc*16 + k];
      s0 += iv[k]   * wk;
      s1 += iv[k+8] * wk;
    }
    float pm = fmaxf(fmaxf(s0, 0.f), fmaxf(s1, 0.f));
    y1[obase + oc*P0] = pm*s_sc[oc] + s_off[oc];
  }
}

// ---------------- conv1 as im2col GEMM: 64m x 128n tiles, K=512, 620 blocks ----------------
// k-major LDS (a stride 66, w stride 132 + XOR swizzle), reg-prefetch pipeline.
__global__ __launch_bounds__(256) void k_conv1_gemm(const float* __restrict__ y1,
    const float* __restrict__ w1, const float* __restrict__ cb1,
    float* __restrict__ tmp) {
  __shared__ __align__(16) float a_t[32*66];
  __shared__ __align__(16) float w_t[32*132];
  int m0 = blockIdx.x * 64;
  int tid = threadIdx.x;
  int sa_s = tid & 7, sa_r = tid >> 3;          // a staging: k-slot(0..7), row(0..31)
  int un = tid & 31, mq = tid >> 5;             // compute: n-quad(0..31), m-group(0..7)
  int ybase[2];
#pragma unroll
  for (int i = 0; i < 2; ++i) {
    int m = m0 + sa_r + 32*i;
    int b = m / 155, t = m - b*155;
    ybase[i] = b*(C0*P0) + 4*t;
  }
  int ci_off = sa_s >> 1, kkq = (sa_s & 1) * 4;
  float4 av[2], wv[4];
  float acc[8][4] = {{0.f}};
  int swzw = sa_s << 2;   // sa_s == sw_q (tid&7), group index for XOR swizzle

#define CONV1_PREFETCH(cidx) do {                                                   \
    int kc = (cidx) * 32;                                                           \
    int ci0 = kc >> 3;                                                              \
    av[0] = *reinterpret_cast<const float4*>(y1 + ybase[0] + (ci0 + ci_off)*P0 + kkq); \
    av[1] = *reinterpret_cast<const float4*>(y1 + ybase[1] + (ci0 + ci_off)*P0 + kkq); \
    _Pragma("unroll")                                                               \
    for (int i = 0; i < 4; ++i)                                                     \
      wv[i] = *reinterpret_cast<const float4*>(w1 + (sa_r + 32*i)*512 + kc + 4*sa_s); \
  } while (0)

  CONV1_PREFETCH(0);
  for (int cidx = 0; cidx < 16; ++cidx) {
    if (cidx) __syncthreads();
#pragma unroll
    for (int i = 0; i < 2; ++i) {
      int col = sa_r + 32*i;
      a_t[(4*sa_s+0)*66 + col] = av[i].x;
      a_t[(4*sa_s+1)*66 + col] = av[i].y;
      a_t[(4*sa_s+2)*66 + col] = av[i].z;
      a_t[(4*sa_s+3)*66 + col] = av[i].w;
    }
#pragma unroll
    for (int i = 0; i < 4; ++i) {
      int colw = (sa_r + 32*i) ^ swzw;
      w_t[(4*sa_s+0)*132 + colw] = wv[i].x;
      w_t[(4*sa_s+1)*132 + colw] = wv[i].y;
      w_t[(4*sa_s+2)*132 + colw] = wv[i].z;
      w_t[(4*sa_s+3)*132 + colw] = wv[i].w;
    }
    __syncthreads();
    if (cidx + 1 < 16) { CONV1_PREFETCH(cidx + 1); }
#pragma unroll
    for (int k = 0; k < 32; ++k) {
      float4 w4 = *reinterpret_cast<const float4*>(&w_t[k*132 + ((4*un) ^ ((k>>2)<<2))]);
      float2 a2[4];
#pragma unroll
      for (int i = 0; i < 4; ++i)
        a2[i] = *reinterpret_cast<const float2*>(&a_t[k*66 + 2*mq + 16*i]);
#pragma unroll
      for (int i = 0; i < 4; ++i) {
        acc[2*i+0][0] += a2[i].x*w4.x; acc[2*i+0][1] += a2[i].x*w4.y;
        acc[2*i+0][2] += a2[i].x*w4.z; acc[2*i+0][3] += a2[i].x*w4.w;
        acc[2*i+1][0] += a2[i].y*w4.x; acc[2*i+1][1] += a2[i].y*w4.y;
        acc[2*i+1][2] += a2[i].y*w4.z; acc[2*i+1][3] += a2[i].y*w4.w;
      }
    }
  }
#undef CONV1_PREFETCH
  float4 bias = *reinterpret_cast<const float4*>(cb1 + 4*un);
#pragma unroll
  for (int i = 0; i < 4; ++i)
#pragma unroll
    for (int jj = 0; jj < 2; ++jj) {
      int m = m0 + 2*mq + 16*i + jj;
      float4 o;
      o.x = acc[2*i+jj][0] + bias.x;
      o.y = acc[2*i+jj][1] + bias.y;
      o.z = acc[2*i+jj][2] + bias.z;
      o.w = acc[2*i+jj][3] + bias.w;
      *reinterpret_cast<float4*>(tmp + m*128 + 4*un) = o;
    }
}

// ---------------- relu + pool2 + bn: tmp -> X (77,256,128) t-major ----------------
__global__ __launch_bounds__(256) void k_pool1(const float* __restrict__ tmp,
    const float* __restrict__ bg1, const float* __restrict__ bb1,
    const float* __restrict__ bm1, const float* __restrict__ bv1,
    float* __restrict__ X) {
  int idx = blockIdx.x*256 + threadIdx.x;
  int u  = idx >> 15;
  int rr = idx & 32767;
  int bb = rr >> 7;
  int oc = rr & 127;
  int base = (bb*155 + 2*u)*128 + oc;
  float t0 = tmp[base], t1 = tmp[base + 128];
  float pm = fmaxf(0.f, fmaxf(t0, t1));
  float sc = bg1[oc] * rsqrtf(bv1[oc] + 1e-5f);
  X[idx] = pm*sc + (bb1[oc] - bm1[oc]*sc);
}

// ---------------- pipelined LSTM step v2 ----------------
// 512 blocks x 128 threads. Per layer 256 blocks = 8 b-tiles(32) x 32 n-tiles(8u x 4g).
// k-major LDS tiles (chunk=64), reg-prefetch pipeline, float2 a-reads + float4 w-reads.
__global__ __launch_bounds__(128) void k_lstm_step(const float* __restrict__ X,
    const float* __restrict__ Wih0, const float* __restrict__ Whh0,
    const float* __restrict__ bih0, const float* __restrict__ bhh0,
    const float* __restrict__ Wih1, const float* __restrict__ Whh1,
    const float* __restrict__ bih1, const float* __restrict__ bhh1,
    float* __restrict__ h0buf, float* __restrict__ c0,
    float* __restrict__ h1buf, float* __restrict__ c1,
    int s) {
  int blk = blockIdx.x;
  int layer = blk >> 8;
  if (layer == 0) { if (s >= 77) return; } else { if (s < 1) return; }
  int lb = blk & 255;
  int b0 = (lb >> 5) * 32;
  int u0 = (lb & 31) * 8;
  int tid = threadIdx.x;
  int un = tid & 7, bq = tid >> 3;   // compute map: u_local, b-pair
  int q = tid & 15, r = tid >> 4;    // staging map: k-quad(0..15), row(0..7)
  const float* h0r = h0buf + (s & 1) * 65536;
  float*       h0w = h0buf + ((s + 1) & 1) * 65536;
  const float* h1r = h1buf + (s & 1) * 65536;
  float*       h1w = h1buf + ((s + 1) & 1) * 65536;
  int t = layer ? (s - 1) : s;

  __shared__ __align__(16) float a_t[64*34];
  __shared__ __align__(16) float w_t[64*36];

  int wrow[4];
#pragma unroll
  for (int i = 0; i < 4; ++i) {
    int c = r + 8*i;
    wrow[i] = (c & 3) * 256 + u0 + (c >> 2);   // PyTorch gate order rows: g*256+u
  }

  const int NC = layer ? 8 : 6;
  float4 av[4], wv[4];

#define LSTM_PREFETCH(cidx) do {                                                  \
    int kc = (cidx) * 64;                                                         \
    const float* ap; int astr, aoff;                                              \
    const float* wp; int wstr, woff;                                              \
    if (layer == 0) {                                                             \
      if (kc < 128) { ap = X + t*32768; astr = 128; aoff = kc;       wp = Wih0; wstr = 128; woff = kc; }       \
      else          { ap = h0r;         astr = 256; aoff = kc - 128; wp = Whh0; wstr = 256; woff = kc - 128; } \
    } else {                                                                      \
      if (kc < 256) { ap = h0r;         astr = 256; aoff = kc;       wp = Wih1; wstr = 256; woff = kc; }       \
      else          { ap = h1r;         astr = 256; aoff = kc - 256; wp = Whh1; wstr = 256; woff = kc - 256; } \
    }                                                                             \
    _Pragma("unroll")                                                             \
    for (int i = 0; i < 4; ++i)                                                   \
      av[i] = *reinterpret_cast<const float4*>(ap + (b0 + r + 8*i) * astr + aoff + 4*q); \
    _Pragma("unroll")                                                             \
    for (int i = 0; i < 4; ++i)                                                   \
      wv[i] = *reinterpret_cast<const float4*>(wp + wrow[i] * wstr + woff + 4*q); \
  } while (0)

  LSTM_PREFETCH(0);
  float acc[2][4] = {{0.f}};
  int swz = (q & 7) << 2;
  for (int cidx = 0; cidx < NC; ++cidx) {
    if (cidx) __syncthreads();
#pragma unroll
    for (int i = 0; i < 4; ++i) {
      int col = r + 8*i;
      a_t[(4*q+0)*34 + col] = av[i].x;
      a_t[(4*q+1)*34 + col] = av[i].y;
      a_t[(4*q+2)*34 + col] = av[i].z;
      a_t[(4*q+3)*34 + col] = av[i].w;
      int colw = col ^ swz;
      w_t[(4*q+0)*36 + colw] = wv[i].x;
      w_t[(4*q+1)*36 + colw] = wv[i].y;
      w_t[(4*q+2)*36 + colw] = wv[i].z;
      w_t[(4*q+3)*36 + colw] = wv[i].w;
    }
    __syncthreads();
    if (cidx + 1 < NC) { LSTM_PREFETCH(cidx + 1); }
#pragma unroll
    for (int k = 0; k < 64; ++k) {
      float2 a2 = *reinterpret_cast<const float2*>(&a_t[k*34 + 2*bq]);
      float4 w4 = *reinterpret_cast<const float4*>(&w_t[k*36 + ((4*un) ^ ((((k>>2)&7))<<2))]);
      acc[0][0] += a2.x * w4.x; acc[0][1] += a2.x * w4.y;
      acc[0][2] += a2.x * w4.z; acc[0][3] += a2.x * w4.w;
      acc[1][0] += a2.y * w4.x; acc[1][1] += a2.y * w4.y;
      acc[1][2] += a2.y * w4.z; acc[1][3] += a2.y * w4.w;
    }
  }
#undef LSTM_PREFETCH

  int uu = u0 + un;
  const float* bi = layer ? bih1 : bih0;
  const float* bh = layer ? bhh1 : bhh0;
  float* cc = layer ? c1 : c0;
  float* hw = layer ? h1w : h0w;
  float bsum[4];
#pragma unroll
  for (int g = 0; g < 4; ++g) bsum[g] = bi[g*256 + uu] + bh[g*256 + uu];
#pragma unroll
  for (int i = 0; i < 2; ++i) {
    int bb = b0 + 2*bq + i;
    float gi = acc[i][0] + bsum[0];
    float gf = acc[i][1] + bsum[1];
    float gg = acc[i][2] + bsum[2];
    float go = acc[i][3] + bsum[3];
    float si = 1.f/(1.f + expf(-gi));
    float sf = 1.f/(1.f + expf(-gf));
    float so = 1.f/(1.f + expf(-go));
    float tg = tanhf(gg);
    float cn = sf*cc[bb*256 + uu] + si*tg;
    cc[bb*256 + uu] = cn;
    hw[bb*256 + uu] = so * tanhf(cn);
  }
}

// ---------------- FC: C = act(A @ W^T + b), M=256 ----------------
__global__ __launch_bounds__(256) void k_fc(const float* __restrict__ A,
    const float* __restrict__ W, const float* __restrict__ bias,
    float* __restrict__ Cout, int N, int K, int kshift, int dorelu) {
  __shared__ __align__(16) float sa[16*516];
  int m0 = blockIdx.y * 16;
  int n = blockIdx.x * 16 + (threadIdx.x & 15);
  int m = threadIdx.x >> 4;
  int stride = K + 4;
  for (int i = threadIdx.x; i < 16*K; i += 256) {
    int mm = i >> kshift;
    int kk = i - (mm << kshift);
    sa[mm*stride + kk] = A[(m0+mm)*K + kk];
  }
  __syncthreads();
  const float4* wr = reinterpret_cast<const float4*>(W + n*K);
  const float4* ar = reinterpret_cast<const float4*>(sa + m*stride);
  float acc = 0.f;
  int kq4 = K >> 2;
  for (int kq = 0; kq < kq4; ++kq) {
    float4 wv = wr[kq], av = ar[kq];
    acc += av.x*wv.x + av.y*wv.y + av.z*wv.z + av.w*wv.w;
  }
  acc += bias[n];
  if (dorelu) acc = fmaxf(acc, 0.f);
  Cout[(m0+m)*N + n] = acc;
}

extern "C" void kernel_launch(void* const* d_in, const int* in_sizes, int n_in,
                              void* d_out, int out_size, void* d_ws, size_t ws_size,
                              hipStream_t stream) {
  const float* x       = (const float*)d_in[0];
  const float* conv_w0 = (const float*)d_in[1];
  const float* conv_b0 = (const float*)d_in[2];
  const float* bn_g0   = (const float*)d_in[3];
  const float* bn_b0   = (const float*)d_in[4];
  const float* bn_m0   = (const float*)d_in[5];
  const float* bn_v0   = (const float*)d_in[6];
  const float* conv_w1 = (const float*)d_in[7];
  const float* conv_b1 = (const float*)d_in[8];
  const float* bn_g1   = (const float*)d_in[9];
  const float* bn_b1   = (const float*)d_in[10];
  const float* bn_m1   = (const float*)d_in[11];
  const float* bn_v1   = (const float*)d_in[12];
  const float* Wih0    = (const float*)d_in[13];
  const float* Whh0    = (const float*)d_in[14];
  const float* bih0    = (const float*)d_in[15];
  const float* bhh0    = (const float*)d_in[16];
  const float* Wih1    = (const float*)d_in[17];
  const float* Whh1    = (const float*)d_in[18];
  const float* bih1    = (const float*)d_in[19];
  const float* bhh1    = (const float*)d_in[20];
  const float* fc0_w   = (const float*)d_in[21];
  const float* fc0_b   = (const float*)d_in[22];
  const float* fc1_w   = (const float*)d_in[23];
  const float* fc1_b   = (const float*)d_in[24];
  const float* out_w   = (const float*)d_in[25];
  const float* out_b   = (const float*)d_in[26];
  float* ws = (float*)d_ws;
  float* out = (float*)d_out;

  static float h_consts[160];
  compute_consts(h_consts);
  hipMemcpyAsync(ws + OFF_CONST, h_consts, 160*sizeof(float), hipMemcpyHostToDevice, stream);
  hipMemsetAsync(ws + OFF_H0, 0, 393216*sizeof(float), stream);

  k_sgconv0<<<dim3(3, BATCH), 256, 0, stream>>>(x, ws + OFF_CONST, conv_w0, conv_b0,
                                                bn_g0, bn_b0, bn_m0, bn_v0, ws + OFF_Y1);
  k_conv1_gemm<<<620, 256, 0, stream>>>(ws + OFF_Y1, conv_w1, conv_b1, ws + OFF_TMP);
  k_pool1<<<9856, 256, 0, stream>>>(ws + OFF_TMP, bn_g1, bn_b1, bn_m1, bn_v1, ws + OFF_X);
  for (int s = 0; s <= 77; ++s) {
    k_lstm_step<<<512, 128, 0, stream>>>(ws + OFF_X, Wih0, Whh0, bih0, bhh0,
                                         Wih1, Whh1, bih1, bhh1,
                                         ws + OFF_H0, ws + OFF_C0, ws + OFF_H1, ws + OFF_C1, s);
  }
  k_fc<<<dim3(32, 16), 256, 0, stream>>>(ws + OFF_H1, fc0_w, fc0_b, ws + OFF_Z0, 512, 256, 8, 1);
  k_fc<<<dim3(32, 16), 256, 0, stream>>>(ws + OFF_Z0, fc1_w, fc1_b, ws + OFF_Z1, 512, 512, 9, 1);
  k_fc<<<dim3(16, 16), 256, 0, stream>>>(ws + OFF_Z1, out_w, out_b, out, 256, 512, 9, 0);
}